// Round 8
// baseline (147.822 us; speedup 1.0000x reference)
//
#include <hip/hip_runtime.h>

// Problem constants (fixed by the reference).
#define NS 4
#define NA 8192
#define NTOK 1024
#define NC 8
#define THREADS 256
#define JSLOTS 4
#define JPB (THREADS * JSLOTS)   // 1024 j-atoms per block
#define TI 64                    // i-atoms per block
#define TPJ (JPB / TI)           // 16 i-tiles per j-tile
#define GRIDX 576                // sum_{jb=0..7} (jb+1)*TPJ

// ws layout:
//   staged[NS*NA] float4 : (2x, 2y, 2z, 2*(thr^2 - sq)) per (s, atom)
//   chain[NA]     int    : per-atom chain id
//   counts[NS*NC*NC] int : global accumulators (zeroed by setup)

__global__ __launch_bounds__(THREADS)
void setup_kernel(const float* __restrict__ coords, const int* __restrict__ asym,
                  const int* __restrict__ a2t, float4* __restrict__ staged,
                  int* __restrict__ chain, int* __restrict__ counts) {
  const float THR2 = 1.21f;  // 1.1^2
  int idx = blockIdx.x * THREADS + threadIdx.x;  // grid covers NS*NA
  float x = coords[3 * idx + 0], y = coords[3 * idx + 1], z = coords[3 * idx + 2];
  staged[idx] = make_float4(2.0f * x, 2.0f * y, 2.0f * z,
                            2.0f * (THR2 - (x * x + y * y + z * z)));
  if (idx < NA) chain[idx] = asym[a2t[idx]];
  if (idx < NS * NC * NC) counts[idx] = 0;
}

// LDS-free, barrier-free: each wave is fully independent. Wave-uniform chain
// ids -> ballot/popc accumulation in SGPRs -> <=8 device atomics per wave.
__global__ __launch_bounds__(THREADS, 8)
void clash_kernel(const float4* __restrict__ staged, const int* __restrict__ chain,
                  int* __restrict__ counts) {
  const int tid = threadIdx.x;
  const int s = blockIdx.z;

  // Decode triangular block index: only i-tiles with i < end(j-tile).
  int f = blockIdx.x, jb = 0;
  while (f >= (jb + 1) * TPJ) { f -= (jb + 1) * TPJ; ++jb; }
  const int ib = f;
  const bool strict = ib < jb * TPJ;  // all i < all j -> mirror not scheduled

  const float4* __restrict__ sb = staged + (size_t)s * NA;
  const float TWO_THR2 = 2.42f;  // 2*1.1^2

  // Per-thread j-atoms (4 slots), coalesced float4 loads from staged.
  float xj[JSLOTS], yj[JSLOTS], zj[JSLOTS], tj2[JSLOTS];
  int bj[JSLOTS];
#pragma unroll
  for (int u = 0; u < JSLOTS; ++u) {
    int j = jb * JPB + u * THREADS + tid;
    float4 cj = sb[j];
    xj[u] = cj.x; yj[u] = cj.y; zj[u] = cj.z;   // = 2*x_j etc.
    tj2[u] = TWO_THR2 - cj.w;                   // = 2*sq_j
    bj[u] = chain[j];
  }

  // i-tile chain id + uniformity, no LDS: per-lane read + wave vote.
  int myi = chain[ib * TI + (tid & 63)];
  const int A = __builtin_amdgcn_readfirstlane(myi);
  bool uniform = __all(myi == A);

  int b0[JSLOTS];
  bool all_same_chain = uniform;
#pragma unroll
  for (int u = 0; u < JSLOTS; ++u) {
    b0[u] = __builtin_amdgcn_readfirstlane(bj[u]);
    bool uu = __all(bj[u] == b0[u]);
    uniform = uniform && uu;
    all_same_chain = all_same_chain && uu && (b0[u] == A);
  }
  // Every pair same-chain -> contributions land on masked diagonal: done.
  if (all_same_chain) return;

  // i-tile via wave-uniform scalar loads (s_load_dwordx4), LDS pipe idle.
  const float4* __restrict__ tg = sb + ib * TI;
  int* __restrict__ cb = counts + s * NC * NC;

  // clash <=> (2xi)(2xj)+(2yi)(2yj)+(2zi)(2zj) + 2*(thr2-sq_i) > 2*sq_j
  if (uniform) {
    int acc[JSLOTS] = {0, 0, 0, 0};
#pragma unroll 8
    for (int t = 0; t < TI; ++t) {
      float4 ci = tg[t];
#pragma unroll
      for (int u = 0; u < JSLOTS; ++u) {
        float d = fmaf(ci.x, xj[u], fmaf(ci.y, yj[u], fmaf(ci.z, zj[u], ci.w)));
        acc[u] += __popcll(__ballot(d > tj2[u]));  // v_cmp->sgpr + s_bcnt1 + s_add
      }
    }
    if ((tid & 63) == 0) {
#pragma unroll
      for (int u = 0; u < JSLOTS; ++u) {
        if (acc[u]) {
          atomicAdd(&cb[A * NC + b0[u]], acc[u]);
          if (strict) atomicAdd(&cb[b0[u] * NC + A], acc[u]);
        }
      }
    }
  } else {
    // robustness path (not hit with this data layout)
    for (int t = 0; t < TI; ++t) {
      float4 ci = tg[t];
      int a = chain[ib * TI + t];
#pragma unroll
      for (int u = 0; u < JSLOTS; ++u) {
        float d = fmaf(ci.x, xj[u], fmaf(ci.y, yj[u], fmaf(ci.z, zj[u], ci.w)));
        if (d > tj2[u]) {
          atomicAdd(&cb[a * NC + bj[u]], 1);
          if (strict) atomicAdd(&cb[bj[u] * NC + a], 1);
        }
      }
    }
  }
}

__global__ __launch_bounds__(THREADS)
void finalize_kernel(const int* __restrict__ asym, const int* __restrict__ counts,
                     float* __restrict__ out) {
  __shared__ int hist[NC];
  int tid = threadIdx.x;
  if (tid < NC) hist[tid] = 0;
  __syncthreads();
  for (int t = tid; t < NTOK; t += THREADS) atomicAdd(&hist[asym[t]], NA / NTOK);
  __syncthreads();

  // tid = s*64 + a*8 + b  (256 threads cover all entries)
  int c = counts[tid];
  int a = (tid >> 3) & 7, b = tid & 7;
  float total = (a == b) ? 0.0f : (float)c;
  float minn = (float)min(hist[a], hist[b]);
  float rel = total / minn;
  out[tid] = ((total > 100.0f) || (rel > 0.5f)) ? 1.0f : 0.0f;
  out[256 + 2 * tid + 0] = total;
  out[256 + 2 * tid + 1] = rel;
}

extern "C" void kernel_launch(void* const* d_in, const int* in_sizes, int n_in,
                              void* d_out, int out_size, void* d_ws, size_t ws_size,
                              hipStream_t stream) {
  const float* coords = (const float*)d_in[0];  // [4, 8192, 3] f32
  const int* asym = (const int*)d_in[1];        // [1024] i32
  const int* a2t = (const int*)d_in[2];         // [8192] i32
  float* out = (float*)d_out;                   // 256 flags + 512 details

  float4* staged = (float4*)d_ws;               // [NS*NA]
  int* chain = (int*)(staged + NS * NA);        // [NA]
  int* counts = chain + NA;                     // [NS*NC*NC]

  setup_kernel<<<dim3(NS * NA / THREADS), THREADS, 0, stream>>>(coords, asym, a2t,
                                                                staged, chain, counts);
  clash_kernel<<<dim3(GRIDX, 1, NS), THREADS, 0, stream>>>(staged, chain, counts);
  finalize_kernel<<<1, THREADS, 0, stream>>>(asym, counts, out);
}

// Round 9
// 78.988 us; speedup vs baseline: 1.8715x; 1.8715x over previous
//
#include <hip/hip_runtime.h>

// Problem constants (fixed by the reference).
#define NS 4
#define NA 8192
#define NTOK 1024
#define NC 8
#define THREADS 256
#define JSLOTS 4
#define JPB (THREADS * JSLOTS)   // 1024 j-atoms per block
#define TI 64                    // i-atoms per block
#define TPJ (JPB / TI)           // 16 i-tiles per j-tile
#define GRIDX 576                // sum_{jb=0..7} (jb+1)*TPJ

// ws layout:
//   staged[NS*NA] float4 : (2x, 2y, 2z, 2*(thr^2 - sq)) per (s, atom)
//   chain[NA]     int    : per-atom chain id
//   counts[NS*NC*NC] int : global accumulators (zeroed by setup)

__global__ __launch_bounds__(THREADS)
void setup_kernel(const float* __restrict__ coords, const int* __restrict__ asym,
                  const int* __restrict__ a2t, float4* __restrict__ staged,
                  int* __restrict__ chain, int* __restrict__ counts) {
  const float THR2 = 1.21f;  // 1.1^2
  int idx = blockIdx.x * THREADS + threadIdx.x;  // grid covers NS*NA
  float x = coords[3 * idx + 0], y = coords[3 * idx + 1], z = coords[3 * idx + 2];
  staged[idx] = make_float4(2.0f * x, 2.0f * y, 2.0f * z,
                            2.0f * (THR2 - (x * x + y * y + z * z)));
  if (idx < NA) chain[idx] = asym[a2t[idx]];
  if (idx < NS * NC * NC) counts[idx] = 0;
}

// Triangle grid + ballot/popc SGPR accumulation + scalar i-tile loads.
// Block-level LDS reduction (red[]) amortizes ~256 wave-results into <=64
// global atomics per block — per-wave global atomics were a 4.5x regression
// (R8: 57K atomics on 16 cachelines serialized at L2).
__global__ __launch_bounds__(THREADS, 8)
void clash_kernel(const float4* __restrict__ staged, const int* __restrict__ chain,
                  int* __restrict__ counts) {
  __shared__ int red[NC * NC];

  const int tid = threadIdx.x;
  const int s = blockIdx.z;

  // Decode triangular block index: only i-tiles with i < end(j-tile).
  int f = blockIdx.x, jb = 0;
  while (f >= (jb + 1) * TPJ) { f -= (jb + 1) * TPJ; ++jb; }
  const int ib = f;
  const bool strict = ib < jb * TPJ;  // all i < all j -> mirror not scheduled

  if (tid < NC * NC) red[tid] = 0;

  const float4* __restrict__ sb = staged + (size_t)s * NA;
  const float TWO_THR2 = 2.42f;  // 2*1.1^2

  // Per-thread j-atoms (4 slots), coalesced float4 loads from staged.
  float xj[JSLOTS], yj[JSLOTS], zj[JSLOTS], tj2[JSLOTS];
  int bj[JSLOTS];
#pragma unroll
  for (int u = 0; u < JSLOTS; ++u) {
    int j = jb * JPB + u * THREADS + tid;
    float4 cj = sb[j];
    xj[u] = cj.x; yj[u] = cj.y; zj[u] = cj.z;   // = 2*x_j etc.
    tj2[u] = TWO_THR2 - cj.w;                   // = 2*sq_j
    bj[u] = chain[j];
  }

  // i-tile chain id + uniformity: per-lane global read + wave votes (no LDS).
  int myi = chain[ib * TI + (tid & 63)];
  const int A = __builtin_amdgcn_readfirstlane(myi);
  bool uniform = __all(myi == A);

  int b0[JSLOTS];
  bool all_same_chain = uniform;
#pragma unroll
  for (int u = 0; u < JSLOTS; ++u) {
    b0[u] = __builtin_amdgcn_readfirstlane(bj[u]);
    bool uu = __all(bj[u] == b0[u]);
    uniform = uniform && uu;
    all_same_chain = all_same_chain && uu && (b0[u] == A);
  }

  __syncthreads();  // red[] init visible to all waves

  // i-tile via wave-uniform scalar loads (s_load_dwordx4), LDS pipe idle.
  const float4* __restrict__ tg = sb + ib * TI;

  // clash <=> (2xi)(2xj)+(2yi)(2yj)+(2zi)(2zj) + 2*(thr2-sq_i) > 2*sq_j
  if (!all_same_chain) {  // all-same-chain -> masked diagonal only: skip work
    if (uniform) {
      int acc[JSLOTS] = {0, 0, 0, 0};
#pragma unroll 8
      for (int t = 0; t < TI; ++t) {
        float4 ci = tg[t];
#pragma unroll
        for (int u = 0; u < JSLOTS; ++u) {
          float d = fmaf(ci.x, xj[u], fmaf(ci.y, yj[u], fmaf(ci.z, zj[u], ci.w)));
          acc[u] += __popcll(__ballot(d > tj2[u]));  // v_cmp + s_bcnt1 + s_add
        }
      }
      if ((tid & 63) == 0) {
#pragma unroll
        for (int u = 0; u < JSLOTS; ++u) {
          if (acc[u]) {
            atomicAdd(&red[A * NC + b0[u]], acc[u]);
            if (strict) atomicAdd(&red[b0[u] * NC + A], acc[u]);
          }
        }
      }
    } else {
      // robustness path (not hit with this data layout)
      for (int t = 0; t < TI; ++t) {
        float4 ci = tg[t];
        int a = chain[ib * TI + t];
#pragma unroll
        for (int u = 0; u < JSLOTS; ++u) {
          float d = fmaf(ci.x, xj[u], fmaf(ci.y, yj[u], fmaf(ci.z, zj[u], ci.w)));
          if (d > tj2[u]) {
            atomicAdd(&red[a * NC + bj[u]], 1);
            if (strict) atomicAdd(&red[bj[u] * NC + a], 1);
          }
        }
      }
    }
  }

  __syncthreads();
  if (tid < NC * NC) {
    int v = red[tid];
    if (v) atomicAdd(&counts[s * NC * NC + tid], v);
  }
}

__global__ __launch_bounds__(THREADS)
void finalize_kernel(const int* __restrict__ asym, const int* __restrict__ counts,
                     float* __restrict__ out) {
  __shared__ int hist[NC];
  int tid = threadIdx.x;
  if (tid < NC) hist[tid] = 0;
  __syncthreads();
  for (int t = tid; t < NTOK; t += THREADS) atomicAdd(&hist[asym[t]], NA / NTOK);
  __syncthreads();

  // tid = s*64 + a*8 + b  (256 threads cover all entries)
  int c = counts[tid];
  int a = (tid >> 3) & 7, b = tid & 7;
  float total = (a == b) ? 0.0f : (float)c;
  float minn = (float)min(hist[a], hist[b]);
  float rel = total / minn;
  out[tid] = ((total > 100.0f) || (rel > 0.5f)) ? 1.0f : 0.0f;
  out[256 + 2 * tid + 0] = total;
  out[256 + 2 * tid + 1] = rel;
}

extern "C" void kernel_launch(void* const* d_in, const int* in_sizes, int n_in,
                              void* d_out, int out_size, void* d_ws, size_t ws_size,
                              hipStream_t stream) {
  const float* coords = (const float*)d_in[0];  // [4, 8192, 3] f32
  const int* asym = (const int*)d_in[1];        // [1024] i32
  const int* a2t = (const int*)d_in[2];         // [8192] i32
  float* out = (float*)d_out;                   // 256 flags + 512 details

  float4* staged = (float4*)d_ws;               // [NS*NA]
  int* chain = (int*)(staged + NS * NA);        // [NA]
  int* counts = chain + NA;                     // [NS*NC*NC]

  setup_kernel<<<dim3(NS * NA / THREADS), THREADS, 0, stream>>>(coords, asym, a2t,
                                                                staged, chain, counts);
  clash_kernel<<<dim3(GRIDX, 1, NS), THREADS, 0, stream>>>(staged, chain, counts);
  finalize_kernel<<<1, THREADS, 0, stream>>>(asym, counts, out);
}